// Round 6
// baseline (383.996 us; speedup 1.0000x reference)
//
#include <hip/hip_runtime.h>
#include <hip/hip_cooperative_groups.h>
#include <math.h>

namespace cg = cooperative_groups;

// Problem constants
static constexpr int N    = 8192;
static constexpr int DIM  = 512;
static constexpr int DK   = 128;
static constexpr int DV   = 128;
static constexpr float SLOPE = 0.01f;

// Scan partitioning: 512 chunks of 16 sorted rows (1 chunk per block)
static constexpr int NCH  = 512;
static constexpr int CHSZ = 16;
static constexpr int NCOL = 258;   // 128 (e1 cols) + 128 (e2 cols) + z1 + z2

// v-GEMM geometry: BM=BN=128 tile, 8x8 per thread, split-K = 4
static constexpr int KSPLIT = 4;
static constexpr int KSUB   = DIM / KSPLIT;   // 128
static constexpr int MT  = 128;
static constexpr int BK  = 32;
static constexpr int LDT = 132;

// ---------------------------------------------------------------------------
// Kernel 1: fused front + v-partials. 512 blocks x 256 threads.
//   blocks [0,256):   v partial GEMM (mt = blk&63, ks = blk>>6)
//   blocks [256,512): front (s_src/s_dst) for rows [(blk-256)*32, +32)
// ---------------------------------------------------------------------------
__global__ __launch_bounds__(256) void k_frontv(const float* __restrict__ x,
                                                const float* __restrict__ W,
                                                const float* __restrict__ b,
                                                const float* __restrict__ a,
                                                const float* __restrict__ Wv,
                                                float* __restrict__ s_src,
                                                float* __restrict__ s_dst,
                                                float* __restrict__ vpart) {
    __shared__ float At[BK][LDT];
    __shared__ float Bt[BK][LDT];
    __shared__ float sa[2 * DK];
    __shared__ float sus[DIM + 32], sud[DIM + 32];
    __shared__ float sc[2];
    int blk = blockIdx.x;
    int tid = threadIdx.x;

    if (blk < 256) {
        // ---------------- v partial GEMM ----------------
        int mt  = blk & 63;
        int ks  = blk >> 6;
        int row0 = mt * MT;
        int kb0  = ks * KSUB;
        int tx = tid & 15, ty = tid >> 4;

        float acc[8][8];
#pragma unroll
        for (int i = 0; i < 8; ++i)
#pragma unroll
            for (int j = 0; j < 8; ++j) acc[i][j] = 0.0f;

        int fr[4], fk[4];
#pragma unroll
        for (int i = 0; i < 4; ++i) {
            int f = tid + i * 256;
            fr[i] = f >> 3;
            fk[i] = (f & 7) * 4;
        }
        float4 px[4], pw[4];
#pragma unroll
        for (int i = 0; i < 4; ++i) {
            px[i] = *reinterpret_cast<const float4*>(x  + (size_t)(row0 + fr[i]) * DIM + kb0 + fk[i]);
            pw[i] = *reinterpret_cast<const float4*>(Wv + (size_t)fr[i] * DIM + kb0 + fk[i]);
        }
        const int nt = KSUB / BK;   // 4
        for (int t = 0; t < nt; ++t) {
#pragma unroll
            for (int i = 0; i < 4; ++i) {
                At[fk[i] + 0][fr[i]] = px[i].x;
                At[fk[i] + 1][fr[i]] = px[i].y;
                At[fk[i] + 2][fr[i]] = px[i].z;
                At[fk[i] + 3][fr[i]] = px[i].w;
                Bt[fk[i] + 0][fr[i]] = pw[i].x;
                Bt[fk[i] + 1][fr[i]] = pw[i].y;
                Bt[fk[i] + 2][fr[i]] = pw[i].z;
                Bt[fk[i] + 3][fr[i]] = pw[i].w;
            }
            __syncthreads();
            if (t < nt - 1) {
                int kb = kb0 + (t + 1) * BK;
#pragma unroll
                for (int i = 0; i < 4; ++i) {
                    px[i] = *reinterpret_cast<const float4*>(x  + (size_t)(row0 + fr[i]) * DIM + kb + fk[i]);
                    pw[i] = *reinterpret_cast<const float4*>(Wv + (size_t)fr[i] * DIM + kb + fk[i]);
                }
            }
#pragma unroll 4
            for (int kk = 0; kk < BK; ++kk) {
                float4 a0 = *reinterpret_cast<const float4*>(&At[kk][ty * 4]);
                float4 a1 = *reinterpret_cast<const float4*>(&At[kk][64 + ty * 4]);
                float4 b0 = *reinterpret_cast<const float4*>(&Bt[kk][tx * 4]);
                float4 b1 = *reinterpret_cast<const float4*>(&Bt[kk][64 + tx * 4]);
                float av[8] = {a0.x, a0.y, a0.z, a0.w, a1.x, a1.y, a1.z, a1.w};
                float bw[8] = {b0.x, b0.y, b0.z, b0.w, b1.x, b1.y, b1.z, b1.w};
#pragma unroll
                for (int i = 0; i < 8; ++i)
#pragma unroll
                    for (int j = 0; j < 8; ++j) acc[i][j] += av[i] * bw[j];
            }
            __syncthreads();
        }
#pragma unroll
        for (int rh = 0; rh < 2; ++rh)
#pragma unroll
            for (int i = 0; i < 4; ++i) {
                int row = row0 + rh * 64 + ty * 4 + i;
                float* dst = vpart + ((size_t)ks * N + row) * DV;
#pragma unroll
                for (int ch = 0; ch < 2; ++ch) {
                    float4 o;
                    o.x = acc[rh * 4 + i][ch * 4 + 0];
                    o.y = acc[rh * 4 + i][ch * 4 + 1];
                    o.z = acc[rh * 4 + i][ch * 4 + 2];
                    o.w = acc[rh * 4 + i][ch * 4 + 3];
                    *reinterpret_cast<float4*>(dst + ch * 64 + tx * 4) = o;
                }
            }
    } else {
        // ---------------- front: s_src / s_dst ----------------
        int fb = blk - 256;
        sa[tid] = a[tid];
        __syncthreads();
        {
            float p = 0.0f;
            if (tid < 64)        p = b[tid] * sa[tid] + b[tid + 64] * sa[tid + 64];
            else if (tid < 128) { int l = tid - 64; p = b[l] * sa[DK + l] + b[l + 64] * sa[DK + 64 + l]; }
#pragma unroll
            for (int off = 32; off > 0; off >>= 1) p += __shfl_down(p, off);
            if (tid == 0)  sc[0] = p;
            if (tid == 64) sc[1] = p;
        }
#pragma unroll
        for (int half = 0; half < 2; ++half) {
            int d = tid + half * 256;
            float us = 0.0f, ud = 0.0f;
#pragma unroll 4
            for (int k = 0; k < DK; ++k) {
                float w = W[(size_t)k * DIM + d];
                us += w * sa[k];
                ud += w * sa[DK + k];
            }
            int dp = d + (d >> 6) * 4;
            sus[dp] = us;
            sud[dp] = ud;
        }
        __syncthreads();
        int r   = tid >> 3;
        int seg = tid & 7;
        int row = fb * 32 + r;
        const float* xr = x + (size_t)row * DIM;
        int base  = seg * 64;
        int baseP = base + seg * 4;
        float accs = 0.0f, accd = 0.0f;
#pragma unroll
        for (int i = 0; i < 16; ++i) {
            float4 q  = *reinterpret_cast<const float4*>(xr + base + i * 4);
            float4 u4 = *reinterpret_cast<const float4*>(&sus[baseP + i * 4]);
            float4 w4 = *reinterpret_cast<const float4*>(&sud[baseP + i * 4]);
            accs += q.x * u4.x + q.y * u4.y + q.z * u4.z + q.w * u4.w;
            accd += q.x * w4.x + q.y * w4.y + q.z * w4.z + q.w * w4.w;
        }
#pragma unroll
        for (int off = 4; off > 0; off >>= 1) {
            accs += __shfl_down(accs, off);
            accd += __shfl_down(accd, off);
        }
        if (seg == 0) {
            s_src[row] = accs + sc[0];
            s_dst[row] = accd + sc[1];
        }
    }
}

// ---------------------------------------------------------------------------
// Phase device functions (shared by coop kernel and fallback kernels)
// ---------------------------------------------------------------------------
__device__ __forceinline__ void rank_phase(int blk, int tid,
                                           const float* __restrict__ s_dst,
                                           float* __restrict__ d_sorted,
                                           int* __restrict__ perm,
                                           float* sd, int* part) {
    for (int t = tid; t < N / 4; t += 256)
        reinterpret_cast<float4*>(sd)[t] = reinterpret_cast<const float4*>(s_dst)[t];
    __syncthreads();
    int j0  = blk * 16;
    int jj  = tid >> 4;
    int seg = tid & 15;
    int j   = j0 + jj;
    float dj = sd[j];
    int cnt = 0;
    const float4* sdv = reinterpret_cast<const float4*>(sd);
    int cbase = seg * 128;
    for (int c = 0; c < 128; ++c) {
        float4 q = sdv[cbase + c];
        int i0 = (cbase + c) * 4;
        cnt += (q.x < dj || (q.x == dj && (i0 + 0) < j));
        cnt += (q.y < dj || (q.y == dj && (i0 + 1) < j));
        cnt += (q.z < dj || (q.z == dj && (i0 + 2) < j));
        cnt += (q.w < dj || (q.w == dj && (i0 + 3) < j));
    }
    part[tid] = cnt;
    __syncthreads();
    if (tid < 16) {
        int s = 0;
#pragma unroll
        for (int t = 0; t < 16; ++t) s += part[tid * 16 + t];
        int jw = j0 + tid;
        d_sorted[s] = sd[jw];
        perm[s] = jw;
    }
}

// C: reduce vpart rows (sorted order) into LDS sv, exp factors, chunk totals
__device__ __forceinline__ void vred_phase(int ch, int tid,
                                           const float* __restrict__ vpart,
                                           const float* __restrict__ bv,
                                           const float* __restrict__ d_sorted,
                                           const int* __restrict__ perm,
                                           double* __restrict__ chunk_tot,
                                           float (*sv)[DV], float* se1, float* se2) {
    float dmax = d_sorted[N - 1];
    if (tid < CHSZ) {
        float d = d_sorted[ch * CHSZ + tid];
        se1[tid] = expf(d - dmax);
        se2[tid] = expf(SLOPE * d);
    }
    __syncthreads();
    int g  = tid >> 5;
    int c4 = tid & 31;
    float4 bb = reinterpret_cast<const float4*>(bv)[c4];
#pragma unroll
    for (int half = 0; half < 2; ++half) {
        int rl = half * 8 + g;
        int r  = ch * CHSZ + rl;
        int j  = perm[r];
        float4 s = {0.f, 0.f, 0.f, 0.f};
#pragma unroll
        for (int ksp = 0; ksp < KSPLIT; ++ksp) {
            float4 q = *reinterpret_cast<const float4*>(vpart + ((size_t)ksp * N + j) * DV + c4 * 4);
            s.x += q.x; s.y += q.y; s.z += q.z; s.w += q.w;
        }
        s.x += bb.x; s.y += bb.y; s.z += bb.z; s.w += bb.w;
        *reinterpret_cast<float4*>(&sv[rl][c4 * 4]) = s;
    }
    __syncthreads();
    int col = tid & 127;
    bool is2 = tid >= 128;
    double acc = 0.0;
#pragma unroll
    for (int k = 0; k < CHSZ; ++k) {
        float e = is2 ? se2[k] : se1[k];
        acc += (double)(e * sv[k][col]);
    }
    chunk_tot[(size_t)ch * NCOL + tid] = acc;
    if (tid == 0) {
        double z = 0.0;
#pragma unroll
        for (int k = 0; k < CHSZ; ++k) z += (double)se1[k];
        chunk_tot[(size_t)ch * NCOL + 256] = z;
    }
    if (tid == 1) {
        double z = 0.0;
#pragma unroll
        for (int k = 0; k < CHSZ; ++k) z += (double)se2[k];
        chunk_tot[(size_t)ch * NCOL + 257] = z;
    }
}

// D: cross-chunk exclusive scan over 512 chunks (blocks 0..257 active)
__device__ __forceinline__ void coff_phase(int blk, int tid,
                                           const double* __restrict__ chunk_tot,
                                           double* __restrict__ chunk_off,
                                           double* __restrict__ totals,
                                           double* sp) {
    if (blk >= NCOL) return;
    int col = blk;
    double v0 = chunk_tot[(size_t)(2 * tid) * NCOL + col];
    double v1 = chunk_tot[(size_t)(2 * tid + 1) * NCOL + col];
    double p = v0 + v1;
    sp[tid] = p;
    __syncthreads();
    for (int off = 1; off < 256; off <<= 1) {
        double t = (tid >= off) ? sp[tid - off] : 0.0;
        __syncthreads();
        sp[tid] += t;
        __syncthreads();
    }
    double excl = sp[tid] - p;
    chunk_off[(size_t)(2 * tid) * NCOL + col]     = excl;
    chunk_off[(size_t)(2 * tid + 1) * NCOL + col] = excl + v0;
    if (tid == 255) totals[col] = sp[255];
}

// E: within-chunk exclusive scan from LDS sv -> P1/P2, pz1/pz2
__device__ __forceinline__ void scan_phase(int ch, int tid,
                                           const double* __restrict__ chunk_off,
                                           float* __restrict__ P1, float* __restrict__ P2,
                                           double* __restrict__ pz1, double* __restrict__ pz2,
                                           const float (*sv)[DV], const float* se1, const float* se2) {
    int col = tid & 127;
    bool is2 = tid >= 128;
    const float* se = is2 ? se2 : se1;
    float* P        = is2 ? P2  : P1;
    double acc = chunk_off[(size_t)ch * NCOL + tid];
#pragma unroll
    for (int k = 0; k < CHSZ; ++k) {
        size_t idx = (size_t)(ch * CHSZ + k) * DV + col;
        P[idx] = (float)acc;
        acc += (double)(se[k] * sv[k][col]);
    }
    if (tid < 2) {
        double z = chunk_off[(size_t)ch * NCOL + 256 + tid];
        const float* sez = (tid == 0) ? se1 : se2;
        double* pz = (tid == 0) ? pz1 : pz2;
#pragma unroll
        for (int k = 0; k < CHSZ; ++k) {
            pz[ch * CHSZ + k] = z;
            z += (double)sez[k];
        }
    }
}

// F: finalize 16 rows per block
__device__ __forceinline__ void final_phase(int blk, int tid,
                                            const float* __restrict__ s_src,
                                            const float* __restrict__ d_sorted,
                                            const float* __restrict__ P1,
                                            const float* __restrict__ P2,
                                            const double* __restrict__ pz1,
                                            const double* __restrict__ pz2,
                                            const double* __restrict__ totals,
                                            float* __restrict__ out,
                                            int* ski, float* ssi) {
    int rbase = blk * 16;
    if (tid < 16) {
        int row = rbase + tid;
        float si = s_src[row];
        float thr = -si;
        int lo = 0, hi = N;
        while (lo < hi) {
            int mid = (lo + hi) >> 1;
            if (d_sorted[mid] <= thr) lo = mid + 1; else hi = mid;
        }
        ski[tid] = lo;
        ssi[tid] = si;
    }
    __syncthreads();
    float dmax = d_sorted[N - 1];
    int dv = tid & 127;
    int half = tid >> 7;
    double T1 = totals[dv];
    double T2 = totals[128 + dv];
    double z1T = totals[256], z2T = totals[257];
#pragma unroll
    for (int it = 0; it < 8; ++it) {
        int r2 = it * 2 + half;
        int row = rbase + r2;
        float si = ssi[r2];
        int ki = ski[r2];
        float t = si + dmax;
        float m = t > 0.0f ? t : SLOPE * t;
        float alpha = expf(t - m);
        float beta  = expf(SLOPE * si - m);
        double suf1, sufz1, pre2, prez2;
        if (ki < N) {
            suf1  = T1 - (double)P1[(size_t)ki * DV + dv];
            sufz1 = z1T - pz1[ki];
            pre2  = (double)P2[(size_t)ki * DV + dv];
            prez2 = pz2[ki];
        } else {
            suf1 = 0.0; sufz1 = 0.0; pre2 = T2; prez2 = z2T;
        }
        double num = (double)alpha * suf1  + (double)beta * pre2;
        double den = (double)alpha * sufz1 + (double)beta * prez2;
        out[(size_t)row * DV + dv] = (float)(num / den);
    }
}

// ---------------------------------------------------------------------------
// Kernel 2: cooperative tail. 512 blocks x 256 threads, 4 grid syncs.
// LDS union: [0,32K) sd | [32K,33K) part   (phase B)
//            [0,8K) sv | [8K..] se1,se2 | sp | ski,ssi  (phases C..F)
// ---------------------------------------------------------------------------
__global__ __launch_bounds__(256) void k_tail(const float* __restrict__ vpart,
                                              const float* __restrict__ bv,
                                              const float* __restrict__ s_src,
                                              const float* __restrict__ s_dst,
                                              float* __restrict__ d_sorted,
                                              int* __restrict__ perm,
                                              double* __restrict__ chunk_tot,
                                              double* __restrict__ chunk_off,
                                              double* __restrict__ totals,
                                              float* __restrict__ P1,
                                              float* __restrict__ P2,
                                              double* __restrict__ pz1,
                                              double* __restrict__ pz2,
                                              float* __restrict__ out) {
    __shared__ __align__(16) unsigned char smem[33792];
    float* sd        = (float*)smem;
    int*   part      = (int*)(smem + 32768);
    float (*sv)[DV]  = (float(*)[DV])smem;
    float* se1       = (float*)(smem + 8192);
    float* se2       = (float*)(smem + 8256);
    double* sp       = (double*)(smem + 8320);
    int*   ski       = (int*)(smem + 10368);
    float* ssi       = (float*)(smem + 10432);

    cg::grid_group grid = cg::this_grid();
    int blk = blockIdx.x;
    int tid = threadIdx.x;

    rank_phase(blk, tid, s_dst, d_sorted, perm, sd, part);
    grid.sync();
    vred_phase(blk, tid, vpart, bv, d_sorted, perm, chunk_tot, sv, se1, se2);
    grid.sync();
    coff_phase(blk, tid, chunk_tot, chunk_off, totals, sp);
    grid.sync();
    scan_phase(blk, tid, chunk_off, P1, P2, pz1, pz2, sv, se1, se2);
    grid.sync();
    final_phase(blk, tid, s_src, d_sorted, P1, P2, pz1, pz2, totals, out, ski, ssi);
}

// ---------------------------------------------------------------------------
// Fallback standalone kernels (used only if cooperative launch fails).
// vredS must persist sv for scanS -> writes Y1/Y2 instead (round-5 scheme).
// ---------------------------------------------------------------------------
__global__ __launch_bounds__(256) void k_rankS(const float* __restrict__ s_dst,
                                               float* __restrict__ d_sorted,
                                               int* __restrict__ perm) {
    __shared__ __align__(16) float sd[N];
    __shared__ int part[256];
    rank_phase(blockIdx.x, threadIdx.x, s_dst, d_sorted, perm, sd, part);
}

__global__ __launch_bounds__(256) void k_vredYS(const float* __restrict__ vpart,
                                                const float* __restrict__ bv,
                                                const float* __restrict__ d_sorted,
                                                const int* __restrict__ perm,
                                                float* __restrict__ Y1,
                                                float* __restrict__ Y2,
                                                double* __restrict__ chunk_tot) {
    __shared__ float sv[CHSZ][DV];
    __shared__ float se1[CHSZ], se2[CHSZ];
    int ch = blockIdx.x, tid = threadIdx.x;
    vred_phase(ch, tid, vpart, bv, d_sorted, perm, chunk_tot, sv, se1, se2);
    __syncthreads();
    // spill sv scaled to Y for the separate scan kernel
    int g  = tid >> 5;
    int c4 = tid & 31;
#pragma unroll
    for (int half = 0; half < 2; ++half) {
        int rl = half * 8 + g;
        int r  = ch * CHSZ + rl;
        float e1 = se1[rl], e2 = se2[rl];
        float4 s = *reinterpret_cast<const float4*>(&sv[rl][c4 * 4]);
        float4 o1 = {e1 * s.x, e1 * s.y, e1 * s.z, e1 * s.w};
        float4 o2 = {e2 * s.x, e2 * s.y, e2 * s.z, e2 * s.w};
        *reinterpret_cast<float4*>(Y1 + (size_t)r * DV + c4 * 4) = o1;
        *reinterpret_cast<float4*>(Y2 + (size_t)r * DV + c4 * 4) = o2;
    }
}

__global__ __launch_bounds__(256) void k_coffS(const double* __restrict__ chunk_tot,
                                               double* __restrict__ chunk_off,
                                               double* __restrict__ totals) {
    __shared__ double sp[256];
    coff_phase(blockIdx.x, threadIdx.x, chunk_tot, chunk_off, totals, sp);
}

__global__ __launch_bounds__(256) void k_scanWS(const float* __restrict__ Y1,
                                                const float* __restrict__ Y2,
                                                const float* __restrict__ d_sorted,
                                                const double* __restrict__ chunk_off,
                                                float* __restrict__ P1,
                                                float* __restrict__ P2,
                                                double* __restrict__ pz1,
                                                double* __restrict__ pz2) {
    int ch  = blockIdx.x;
    int tid = threadIdx.x;
    int col = tid & 127;
    bool is2 = tid >= 128;
    const float* Y = is2 ? Y2 : Y1;
    float* P       = is2 ? P2 : P1;
    double acc = chunk_off[(size_t)ch * NCOL + tid];
#pragma unroll
    for (int k = 0; k < CHSZ; ++k) {
        size_t idx = (size_t)(ch * CHSZ + k) * DV + col;
        P[idx] = (float)acc;
        acc += (double)Y[idx];
    }
    if (tid < 2) {
        float dmax = d_sorted[N - 1];
        double z = chunk_off[(size_t)ch * NCOL + 256 + tid];
        double* pz = tid == 0 ? pz1 : pz2;
#pragma unroll
        for (int k = 0; k < CHSZ; ++k) {
            int r = ch * CHSZ + k;
            float d = d_sorted[r];
            float e = (tid == 0) ? expf(d - dmax) : expf(SLOPE * d);
            pz[r] = z;
            z += (double)e;
        }
    }
}

__global__ __launch_bounds__(256) void k_finalS(const float* __restrict__ s_src,
                                                const float* __restrict__ d_sorted,
                                                const float* __restrict__ P1,
                                                const float* __restrict__ P2,
                                                const double* __restrict__ pz1,
                                                const double* __restrict__ pz2,
                                                const double* __restrict__ totals,
                                                float* __restrict__ out) {
    __shared__ int ski[16];
    __shared__ float ssi[16];
    final_phase(blockIdx.x, threadIdx.x, s_src, d_sorted, P1, P2, pz1, pz2, totals, out, ski, ssi);
}

// ---------------------------------------------------------------------------
extern "C" void kernel_launch(void* const* d_in, const int* in_sizes, int n_in,
                              void* d_out, int out_size, void* d_ws, size_t ws_size,
                              hipStream_t stream) {
    const float* x  = (const float*)d_in[0];
    const float* W  = (const float*)d_in[1];
    const float* b  = (const float*)d_in[2];
    const float* Wv = (const float*)d_in[3];
    const float* bv = (const float*)d_in[4];
    const float* a  = (const float*)d_in[5];
    float* out = (float*)d_out;

    char* base = (char*)d_ws;
    size_t off = 0;
    auto carve = [&](size_t bytes) -> void* {
        void* p = base + off;
        off = (off + bytes + 255) & ~(size_t)255;
        return p;
    };
    float*  s_src     = (float*)carve(N * sizeof(float));
    float*  s_dst     = (float*)carve(N * sizeof(float));
    float*  d_sorted  = (float*)carve(N * sizeof(float));
    int*    perm      = (int*)carve(N * sizeof(int));
    double* pz1       = (double*)carve(N * sizeof(double));
    double* pz2       = (double*)carve(N * sizeof(double));
    double* chunk_tot = (double*)carve((size_t)NCH * NCOL * sizeof(double));
    double* chunk_off = (double*)carve((size_t)NCH * NCOL * sizeof(double));
    double* totals    = (double*)carve(NCOL * sizeof(double));
    float*  Y1        = (float*)carve((size_t)N * DV * sizeof(float));   // fallback only
    float*  Y2        = (float*)carve((size_t)N * DV * sizeof(float));   // fallback only

    // Union: vpart (KSPLIT * 4 MB, dead after vred phase) aliases P1/P2
    // (8 MB, written in scan phase). 16 MB total; overall ws use ~26 MB.
    const size_t planeB = (size_t)N * DV * sizeof(float);   // 4 MB
    char* uni = (char*)carve((size_t)KSPLIT * planeB);
    float* vpart = (float*)uni;
    float* P1    = (float*)uni;
    float* P2    = (float*)(uni + planeB);

    k_frontv<<<512, 256, 0, stream>>>(x, W, b, a, Wv, s_src, s_dst, vpart);

    void* args[] = {
        (void*)&vpart, (void*)&bv, (void*)&s_src, (void*)&s_dst,
        (void*)&d_sorted, (void*)&perm, (void*)&chunk_tot, (void*)&chunk_off,
        (void*)&totals, (void*)&P1, (void*)&P2, (void*)&pz1, (void*)&pz2,
        (void*)&out
    };
    hipError_t err = hipLaunchCooperativeKernel((const void*)k_tail,
                                                dim3(NCH), dim3(256),
                                                args, 0, stream);
    if (err != hipSuccess) {
        // Fallback: round-5 proven multi-kernel tail
        k_rankS<<<NCH, 256, 0, stream>>>(s_dst, d_sorted, perm);
        k_vredYS<<<NCH, 256, 0, stream>>>(vpart, bv, d_sorted, perm, Y1, Y2, chunk_tot);
        k_coffS<<<NCOL, 256, 0, stream>>>(chunk_tot, chunk_off, totals);
        k_scanWS<<<NCH, 256, 0, stream>>>(Y1, Y2, d_sorted, chunk_off, P1, P2, pz1, pz2);
        k_finalS<<<NCH, 256, 0, stream>>>(s_src, d_sorted, P1, P2, pz1, pz2, totals, out);
    }
}

// Round 7
// 160.091 us; speedup vs baseline: 2.3986x; 2.3986x over previous
//
#include <hip/hip_runtime.h>
#include <math.h>

// Problem constants
static constexpr int N    = 8192;
static constexpr int DIM  = 512;
static constexpr int DK   = 128;
static constexpr int DV   = 128;
static constexpr float SLOPE = 0.01f;

// Scan partitioning: 512 chunks of 16 sorted rows
static constexpr int NCH  = 512;
static constexpr int CHSZ = 16;
static constexpr int NCOL = 258;   // 128 (e1 cols) + 128 (e2 cols) + z1 + z2

// k_v geometry: BM=BN=128 tile, 8x8 per thread, split-K chosen at launch
static constexpr int MT  = 128;
static constexpr int BK  = 32;
static constexpr int LDT = 132;    // padded LDS row stride

// ---------------------------------------------------------------------------
// K1 fused front: per block compute u_src/u_dst = W^T a halves (redundant, in
// padded LDS) + c0/c1 = b.a halves, then s_src/s_dst for 32 rows. 256 blocks.
// ---------------------------------------------------------------------------
__global__ __launch_bounds__(256) void k_front(const float* __restrict__ x,
                                               const float* __restrict__ W,
                                               const float* __restrict__ b,
                                               const float* __restrict__ a,
                                               float* __restrict__ s_src,
                                               float* __restrict__ s_dst) {
    __shared__ float sa[2 * DK];
    __shared__ float sus[DIM + 32], sud[DIM + 32];  // idx d -> d + (d>>6)*4
    __shared__ float sc[2];
    int tid = threadIdx.x;
    sa[tid] = a[tid];
    __syncthreads();

    {   // c0/c1: wave 0 reduces b.a[:128], wave 1 reduces b.a[128:]
        float p = 0.0f;
        if (tid < 64)        p = b[tid] * sa[tid] + b[tid + 64] * sa[tid + 64];
        else if (tid < 128) { int l = tid - 64; p = b[l] * sa[DK + l] + b[l + 64] * sa[DK + 64 + l]; }
#pragma unroll
        for (int off = 32; off > 0; off >>= 1) p += __shfl_down(p, off);
        if (tid == 0)  sc[0] = p;
        if (tid == 64) sc[1] = p;
    }

#pragma unroll
    for (int half = 0; half < 2; ++half) {
        int d = tid + half * 256;
        float us = 0.0f, ud = 0.0f;
#pragma unroll 4
        for (int k = 0; k < DK; ++k) {
            float w = W[(size_t)k * DIM + d];
            us += w * sa[k];
            ud += w * sa[DK + k];
        }
        int dp = d + (d >> 6) * 4;
        sus[dp] = us;
        sud[dp] = ud;
    }
    __syncthreads();

    int r   = tid >> 3;
    int seg = tid & 7;
    int row = blockIdx.x * 32 + r;
    const float* xr = x + (size_t)row * DIM;
    int base  = seg * 64;
    int baseP = base + seg * 4;
    float accs = 0.0f, accd = 0.0f;
#pragma unroll
    for (int i = 0; i < 16; ++i) {
        float4 q  = *reinterpret_cast<const float4*>(xr + base + i * 4);
        float4 u4 = *reinterpret_cast<const float4*>(&sus[baseP + i * 4]);
        float4 w4 = *reinterpret_cast<const float4*>(&sud[baseP + i * 4]);
        accs += q.x * u4.x + q.y * u4.y + q.z * u4.z + q.w * u4.w;
        accd += q.x * w4.x + q.y * w4.y + q.z * w4.z + q.w * w4.w;
    }
#pragma unroll
    for (int off = 4; off > 0; off >>= 1) {
        accs += __shfl_down(accs, off);
        accd += __shfl_down(accd, off);
    }
    if (seg == 0) {
        s_src[row] = accs + sc[0];
        s_dst[row] = accd + sc[1];
    }
}

// ---------------------------------------------------------------------------
// K2: v partials. grid = 64 m-tiles x ksplit, 256 threads. BM=BN=128, 8x8
// thread tile, A/B transposed in LDS ([BK][LDT]) -> conflict-free b128 reads.
// ---------------------------------------------------------------------------
__global__ __launch_bounds__(256) void k_v(const float* __restrict__ x,
                                           const float* __restrict__ Wv,
                                           float* __restrict__ vpart, int ksplit) {
    __shared__ float At[BK][LDT];
    __shared__ float Bt[BK][LDT];
    int tid = threadIdx.x;
    int mt  = blockIdx.x & 63;
    int ks  = blockIdx.x >> 6;
    int row0 = mt * MT;
    int ksub = DIM / ksplit;
    int kb0  = ks * ksub;
    int nt   = ksub / BK;
    int tx = tid & 15, ty = tid >> 4;

    float acc[8][8];
#pragma unroll
    for (int i = 0; i < 8; ++i)
#pragma unroll
        for (int j = 0; j < 8; ++j) acc[i][j] = 0.0f;

    int fr[4], fk[4];
#pragma unroll
    for (int i = 0; i < 4; ++i) {
        int f = tid + i * 256;
        fr[i] = f >> 3;          // 0..127
        fk[i] = (f & 7) * 4;     // 0,4,..,28
    }
    float4 px[4], pw[4];
#pragma unroll
    for (int i = 0; i < 4; ++i) {
        px[i] = *reinterpret_cast<const float4*>(x  + (size_t)(row0 + fr[i]) * DIM + kb0 + fk[i]);
        pw[i] = *reinterpret_cast<const float4*>(Wv + (size_t)fr[i] * DIM + kb0 + fk[i]);
    }

    for (int t = 0; t < nt; ++t) {
#pragma unroll
        for (int i = 0; i < 4; ++i) {
            At[fk[i] + 0][fr[i]] = px[i].x;
            At[fk[i] + 1][fr[i]] = px[i].y;
            At[fk[i] + 2][fr[i]] = px[i].z;
            At[fk[i] + 3][fr[i]] = px[i].w;
            Bt[fk[i] + 0][fr[i]] = pw[i].x;
            Bt[fk[i] + 1][fr[i]] = pw[i].y;
            Bt[fk[i] + 2][fr[i]] = pw[i].z;
            Bt[fk[i] + 3][fr[i]] = pw[i].w;
        }
        __syncthreads();
        if (t < nt - 1) {
            int kb = kb0 + (t + 1) * BK;
#pragma unroll
            for (int i = 0; i < 4; ++i) {
                px[i] = *reinterpret_cast<const float4*>(x  + (size_t)(row0 + fr[i]) * DIM + kb + fk[i]);
                pw[i] = *reinterpret_cast<const float4*>(Wv + (size_t)fr[i] * DIM + kb + fk[i]);
            }
        }
#pragma unroll 4
        for (int kk = 0; kk < BK; ++kk) {
            float4 a0 = *reinterpret_cast<const float4*>(&At[kk][ty * 4]);
            float4 a1 = *reinterpret_cast<const float4*>(&At[kk][64 + ty * 4]);
            float4 b0 = *reinterpret_cast<const float4*>(&Bt[kk][tx * 4]);
            float4 b1 = *reinterpret_cast<const float4*>(&Bt[kk][64 + tx * 4]);
            float av[8] = {a0.x, a0.y, a0.z, a0.w, a1.x, a1.y, a1.z, a1.w};
            float bw[8] = {b0.x, b0.y, b0.z, b0.w, b1.x, b1.y, b1.z, b1.w};
#pragma unroll
            for (int i = 0; i < 8; ++i)
#pragma unroll
                for (int j = 0; j < 8; ++j) acc[i][j] += av[i] * bw[j];
        }
        __syncthreads();
    }

#pragma unroll
    for (int rh = 0; rh < 2; ++rh)
#pragma unroll
        for (int i = 0; i < 4; ++i) {
            int row = row0 + rh * 64 + ty * 4 + i;
            float* dst = vpart + ((size_t)ks * N + row) * DV;
#pragma unroll
            for (int ch = 0; ch < 2; ++ch) {
                float4 o;
                o.x = acc[rh * 4 + i][ch * 4 + 0];
                o.y = acc[rh * 4 + i][ch * 4 + 1];
                o.z = acc[rh * 4 + i][ch * 4 + 2];
                o.w = acc[rh * 4 + i][ch * 4 + 3];
                *reinterpret_cast<float4*>(dst + ch * 64 + tx * 4) = o;
            }
        }
}

// ---------------------------------------------------------------------------
// K3: rank + scatter fused. 512 blocks; block owns 16 j's, full s_dst in LDS.
// CONFLICT-FIX vs round 5: seg-groups traverse f4 = c*16 + seg so the 16
// lanes of a group read CONSECUTIVE float4s (conflict-free; the 4 jj-groups
// per wave read identical addresses = broadcast). Round-6 profile showed
// 1.57e7 LDS bank-conflict cycles (~25 us) from the old seg*128 + c layout.
// ---------------------------------------------------------------------------
__global__ __launch_bounds__(256) void k_rank_scatter(const float* __restrict__ s_dst,
                                                      float* __restrict__ d_sorted,
                                                      int* __restrict__ perm) {
    __shared__ __align__(16) float sd[N];
    __shared__ int part[256];
    int tid = threadIdx.x;
    for (int t = tid; t < N / 4; t += 256)
        reinterpret_cast<float4*>(sd)[t] = reinterpret_cast<const float4*>(s_dst)[t];
    __syncthreads();
    int j0  = blockIdx.x * 16;
    int jj  = tid >> 4;          // which j (0..15)
    int seg = tid & 15;          // which slice (0..15)
    int j   = j0 + jj;
    float dj = sd[j];
    int cnt = 0;
    const float4* sdv = reinterpret_cast<const float4*>(sd);
    for (int c = 0; c < 128; ++c) {
        int f4 = c * 16 + seg;   // lanes of a seg-group -> consecutive float4
        float4 q = sdv[f4];
        int i0 = f4 * 4;
        cnt += (q.x < dj || (q.x == dj && (i0 + 0) < j));
        cnt += (q.y < dj || (q.y == dj && (i0 + 1) < j));
        cnt += (q.z < dj || (q.z == dj && (i0 + 2) < j));
        cnt += (q.w < dj || (q.w == dj && (i0 + 3) < j));
    }
    part[tid] = cnt;
    __syncthreads();
    if (tid < 16) {
        int s = 0;
#pragma unroll
        for (int t = 0; t < 16; ++t) s += part[tid * 16 + t];
        int jw = j0 + tid;
        d_sorted[s] = sd[jw];
        perm[s] = jw;
    }
}

// ---------------------------------------------------------------------------
// K4: fused vred + permute + scale + chunk totals. 512 blocks x 16 sorted rows.
// ---------------------------------------------------------------------------
__global__ __launch_bounds__(256) void k_vredY(const float* __restrict__ vpart,
                                               const float* __restrict__ bv,
                                               const float* __restrict__ d_sorted,
                                               const int* __restrict__ perm,
                                               float* __restrict__ Y1,
                                               float* __restrict__ Y2,
                                               double* __restrict__ chunk_tot,
                                               int ksplit) {
    __shared__ float sv[CHSZ][DV];    // unscaled vrows
    __shared__ float se1[CHSZ], se2[CHSZ];
    int ch  = blockIdx.x;
    int tid = threadIdx.x;
    int g   = tid >> 5;               // 0..7 row subgroup
    int c4  = tid & 31;               // float4 col
    float dmax = d_sorted[N - 1];
    if (tid < CHSZ) {
        float d = d_sorted[ch * CHSZ + tid];
        se1[tid] = expf(d - dmax);
        se2[tid] = expf(SLOPE * d);
    }
    __syncthreads();
    float4 bb = reinterpret_cast<const float4*>(bv)[c4];
#pragma unroll
    for (int half = 0; half < 2; ++half) {
        int rl = half * 8 + g;
        int r  = ch * CHSZ + rl;
        int j  = perm[r];
        float4 s = {0.f, 0.f, 0.f, 0.f};
        for (int ksp = 0; ksp < ksplit; ++ksp) {
            float4 q = *reinterpret_cast<const float4*>(vpart + ((size_t)ksp * N + j) * DV + c4 * 4);
            s.x += q.x; s.y += q.y; s.z += q.z; s.w += q.w;
        }
        s.x += bb.x; s.y += bb.y; s.z += bb.z; s.w += bb.w;
        *reinterpret_cast<float4*>(&sv[rl][c4 * 4]) = s;
        float e1 = se1[rl], e2 = se2[rl];
        float4 o1 = {e1 * s.x, e1 * s.y, e1 * s.z, e1 * s.w};
        float4 o2 = {e2 * s.x, e2 * s.y, e2 * s.z, e2 * s.w};
        *reinterpret_cast<float4*>(Y1 + (size_t)r * DV + c4 * 4) = o1;
        *reinterpret_cast<float4*>(Y2 + (size_t)r * DV + c4 * 4) = o2;
    }
    __syncthreads();
    int col = tid & 127;
    bool is2 = tid >= 128;
    double acc = 0.0;
#pragma unroll
    for (int k = 0; k < CHSZ; ++k) {
        float e = is2 ? se2[k] : se1[k];
        acc += (double)(e * sv[k][col]);
    }
    chunk_tot[(size_t)ch * NCOL + tid] = acc;
    if (tid == 0) {
        double z = 0.0;
#pragma unroll
        for (int k = 0; k < CHSZ; ++k) z += (double)se1[k];
        chunk_tot[(size_t)ch * NCOL + 256] = z;
    }
    if (tid == 1) {
        double z = 0.0;
#pragma unroll
        for (int k = 0; k < CHSZ; ++k) z += (double)se2[k];
        chunk_tot[(size_t)ch * NCOL + 257] = z;
    }
}

// ---------------------------------------------------------------------------
// K5: cross-chunk exclusive scan over 512 chunks. 258 blocks x 256 thr;
// each thread owns chunk pair (2t, 2t+1); Hillis-Steele over pair sums.
// ---------------------------------------------------------------------------
__global__ __launch_bounds__(256) void k_coff(const double* __restrict__ chunk_tot,
                                              double* __restrict__ chunk_off,
                                              double* __restrict__ totals) {
    __shared__ double sp[256];
    int col = blockIdx.x;
    int tid = threadIdx.x;
    double v0 = chunk_tot[(size_t)(2 * tid) * NCOL + col];
    double v1 = chunk_tot[(size_t)(2 * tid + 1) * NCOL + col];
    double p = v0 + v1;
    sp[tid] = p;
    __syncthreads();
    for (int off = 1; off < 256; off <<= 1) {
        double t = (tid >= off) ? sp[tid - off] : 0.0;
        __syncthreads();
        sp[tid] += t;
        __syncthreads();
    }
    double excl = sp[tid] - p;
    chunk_off[(size_t)(2 * tid) * NCOL + col]     = excl;
    chunk_off[(size_t)(2 * tid + 1) * NCOL + col] = excl + v0;
    if (tid == 255) totals[col] = sp[255];
}

// ---------------------------------------------------------------------------
// K6: within-chunk exclusive scans over contiguous Y -> P1, P2 (float),
// pz1/pz2 (double). 512 blocks; fully coalesced loads/stores.
// ---------------------------------------------------------------------------
__global__ __launch_bounds__(256) void k_scanW(const float* __restrict__ Y1,
                                               const float* __restrict__ Y2,
                                               const float* __restrict__ d_sorted,
                                               const double* __restrict__ chunk_off,
                                               float* __restrict__ P1,
                                               float* __restrict__ P2,
                                               double* __restrict__ pz1,
                                               double* __restrict__ pz2) {
    int ch  = blockIdx.x;
    int tid = threadIdx.x;
    int col = tid & 127;
    bool is2 = tid >= 128;
    const float* Y = is2 ? Y2 : Y1;
    float* P       = is2 ? P2 : P1;
    double acc = chunk_off[(size_t)ch * NCOL + tid];
#pragma unroll
    for (int k = 0; k < CHSZ; ++k) {
        size_t idx = (size_t)(ch * CHSZ + k) * DV + col;
        P[idx] = (float)acc;
        acc += (double)Y[idx];
    }
    if (tid < 2) {
        float dmax = d_sorted[N - 1];
        double z = chunk_off[(size_t)ch * NCOL + 256 + tid];
        double* pz = tid == 0 ? pz1 : pz2;
#pragma unroll
        for (int k = 0; k < CHSZ; ++k) {
            int r = ch * CHSZ + k;
            float d = d_sorted[r];
            float e = (tid == 0) ? expf(d - dmax) : expf(SLOPE * d);
            pz[r] = z;
            z += (double)e;
        }
    }
}

// ---------------------------------------------------------------------------
// K7: finalize. 1024 blocks x 256 thr; 8 rows/block; searches hoisted.
// ---------------------------------------------------------------------------
__global__ __launch_bounds__(256) void k_final(const float* __restrict__ s_src,
                                               const float* __restrict__ d_sorted,
                                               const float* __restrict__ P1,
                                               const float* __restrict__ P2,
                                               const double* __restrict__ pz1,
                                               const double* __restrict__ pz2,
                                               const double* __restrict__ totals,
                                               float* __restrict__ out) {
    __shared__ int ski[8];
    __shared__ float ssi[8];
    int tid = threadIdx.x;
    int rbase = blockIdx.x * 8;
    if (tid < 8) {
        int row = rbase + tid;
        float si = s_src[row];
        float thr = -si;
        int lo = 0, hi = N;
        while (lo < hi) {
            int mid = (lo + hi) >> 1;
            if (d_sorted[mid] <= thr) lo = mid + 1; else hi = mid;
        }
        ski[tid] = lo;
        ssi[tid] = si;
    }
    __syncthreads();
    float dmax = d_sorted[N - 1];
    int dv = tid & 127;
    int half = tid >> 7;
    double T1 = totals[dv];
    double T2 = totals[128 + dv];
    double z1T = totals[256], z2T = totals[257];
#pragma unroll
    for (int it = 0; it < 4; ++it) {
        int r2 = it * 2 + half;
        int row = rbase + r2;
        float si = ssi[r2];
        int ki = ski[r2];
        float t = si + dmax;
        float m = t > 0.0f ? t : SLOPE * t;
        float alpha = expf(t - m);
        float beta  = expf(SLOPE * si - m);
        double suf1, sufz1, pre2, prez2;
        if (ki < N) {
            suf1  = T1 - (double)P1[(size_t)ki * DV + dv];
            sufz1 = z1T - pz1[ki];
            pre2  = (double)P2[(size_t)ki * DV + dv];
            prez2 = pz2[ki];
        } else {
            suf1 = 0.0; sufz1 = 0.0; pre2 = T2; prez2 = z2T;
        }
        double num = (double)alpha * suf1  + (double)beta * pre2;
        double den = (double)alpha * sufz1 + (double)beta * prez2;
        out[(size_t)row * DV + dv] = (float)(num / den);
    }
}

// ---------------------------------------------------------------------------
extern "C" void kernel_launch(void* const* d_in, const int* in_sizes, int n_in,
                              void* d_out, int out_size, void* d_ws, size_t ws_size,
                              hipStream_t stream) {
    const float* x  = (const float*)d_in[0];
    const float* W  = (const float*)d_in[1];
    const float* b  = (const float*)d_in[2];
    const float* Wv = (const float*)d_in[3];
    const float* bv = (const float*)d_in[4];
    const float* a  = (const float*)d_in[5];
    float* out = (float*)d_out;

    char* base = (char*)d_ws;
    size_t off = 0;
    auto carve = [&](size_t bytes) -> void* {
        void* p = base + off;
        off = (off + bytes + 255) & ~(size_t)255;
        return p;
    };
    float*  s_src     = (float*)carve(N * sizeof(float));
    float*  s_dst     = (float*)carve(N * sizeof(float));
    float*  d_sorted  = (float*)carve(N * sizeof(float));
    int*    perm      = (int*)carve(N * sizeof(int));
    double* pz1       = (double*)carve(N * sizeof(double));
    double* pz2       = (double*)carve(N * sizeof(double));
    double* chunk_tot = (double*)carve((size_t)NCH * NCOL * sizeof(double));
    double* chunk_off = (double*)carve((size_t)NCH * NCOL * sizeof(double));
    double* totals    = (double*)carve(NCOL * sizeof(double));
    float*  Y1        = (float*)carve((size_t)N * DV * sizeof(float));
    float*  Y2        = (float*)carve((size_t)N * DV * sizeof(float));

    // Union region: vpart (ksplit * 4 MB, dead after k_vredY) aliases
    // P1/P2 (8 MB, written later in k_scanW). ksplit adapts to ws_size.
    const size_t planeB = (size_t)N * DV * sizeof(float);   // 4 MB
    size_t avail = ws_size > off ? ws_size - off : 0;
    int ksplit = 2;
    if (avail >= 8 * planeB + 4096)      ksplit = 8;
    else if (avail >= 4 * planeB + 4096) ksplit = 4;
    if (ksplit == 8) ksplit = 4;   // 4 is the traffic/occupancy sweet spot
    size_t unionBytes = (size_t)(ksplit > 2 ? ksplit : 2) * planeB;
    char* uni = (char*)carve(unionBytes);
    float* vpart = (float*)uni;
    float* P1    = (float*)uni;
    float* P2    = (float*)(uni + planeB);

    k_front<<<N / 32, 256, 0, stream>>>(x, W, b, a, s_src, s_dst);
    k_v<<<64 * ksplit, 256, 0, stream>>>(x, Wv, vpart, ksplit);
    k_rank_scatter<<<N / 16, 256, 0, stream>>>(s_dst, d_sorted, perm);
    k_vredY<<<NCH, 256, 0, stream>>>(vpart, bv, d_sorted, perm, Y1, Y2, chunk_tot, ksplit);
    k_coff<<<NCOL, 256, 0, stream>>>(chunk_tot, chunk_off, totals);
    k_scanW<<<NCH, 256, 0, stream>>>(Y1, Y2, d_sorted, chunk_off, P1, P2, pz1, pz2);
    k_final<<<N / 8, 256, 0, stream>>>(s_src, d_sorted, P1, P2, pz1, pz2, totals, out);
}

// Round 8
// 139.337 us; speedup vs baseline: 2.7559x; 1.1489x over previous
//
#include <hip/hip_runtime.h>
#include <math.h>

// Problem constants
static constexpr int N    = 8192;
static constexpr int DIM  = 512;
static constexpr int DK   = 128;
static constexpr int DV   = 128;
static constexpr float SLOPE = 0.01f;

// Scan partitioning: 512 chunks of 16 sorted rows
static constexpr int NCH  = 512;
static constexpr int CHSZ = 16;
static constexpr int NCOL = 258;   // 128 (e1 cols) + 128 (e2 cols) + z1 + z2

// v-GEMM geometry: BM=BN=128 tile, 8x8 per thread
static constexpr int MT  = 128;
static constexpr int BK  = 32;
static constexpr int LDT = 132;    // padded LDS row stride
static constexpr int KSPLIT = 4;   // fused-path split-K
static constexpr int KSUB   = DIM / KSPLIT;

// ---------------------------------------------------------------------------
// GEMM partial device body (tile mt, k-split ks, ksub K columns)
// ---------------------------------------------------------------------------
__device__ __forceinline__ void gemm_body(int mt, int ks, int ksub, int tid,
                                          const float* __restrict__ x,
                                          const float* __restrict__ Wv,
                                          float* __restrict__ vpart,
                                          float (*At)[LDT], float (*Bt)[LDT]) {
    int row0 = mt * MT;
    int kb0  = ks * ksub;
    int nt   = ksub / BK;
    int tx = tid & 15, ty = tid >> 4;

    float acc[8][8];
#pragma unroll
    for (int i = 0; i < 8; ++i)
#pragma unroll
        for (int j = 0; j < 8; ++j) acc[i][j] = 0.0f;

    int fr[4], fk[4];
#pragma unroll
    for (int i = 0; i < 4; ++i) {
        int f = tid + i * 256;
        fr[i] = f >> 3;          // 0..127
        fk[i] = (f & 7) * 4;     // 0,4,..,28
    }
    float4 px[4], pw[4];
#pragma unroll
    for (int i = 0; i < 4; ++i) {
        px[i] = *reinterpret_cast<const float4*>(x  + (size_t)(row0 + fr[i]) * DIM + kb0 + fk[i]);
        pw[i] = *reinterpret_cast<const float4*>(Wv + (size_t)fr[i] * DIM + kb0 + fk[i]);
    }

    for (int t = 0; t < nt; ++t) {
#pragma unroll
        for (int i = 0; i < 4; ++i) {
            At[fk[i] + 0][fr[i]] = px[i].x;
            At[fk[i] + 1][fr[i]] = px[i].y;
            At[fk[i] + 2][fr[i]] = px[i].z;
            At[fk[i] + 3][fr[i]] = px[i].w;
            Bt[fk[i] + 0][fr[i]] = pw[i].x;
            Bt[fk[i] + 1][fr[i]] = pw[i].y;
            Bt[fk[i] + 2][fr[i]] = pw[i].z;
            Bt[fk[i] + 3][fr[i]] = pw[i].w;
        }
        __syncthreads();
        if (t < nt - 1) {
            int kb = kb0 + (t + 1) * BK;
#pragma unroll
            for (int i = 0; i < 4; ++i) {
                px[i] = *reinterpret_cast<const float4*>(x  + (size_t)(row0 + fr[i]) * DIM + kb + fk[i]);
                pw[i] = *reinterpret_cast<const float4*>(Wv + (size_t)fr[i] * DIM + kb + fk[i]);
            }
        }
#pragma unroll 4
        for (int kk = 0; kk < BK; ++kk) {
            float4 a0 = *reinterpret_cast<const float4*>(&At[kk][ty * 4]);
            float4 a1 = *reinterpret_cast<const float4*>(&At[kk][64 + ty * 4]);
            float4 b0 = *reinterpret_cast<const float4*>(&Bt[kk][tx * 4]);
            float4 b1 = *reinterpret_cast<const float4*>(&Bt[kk][64 + tx * 4]);
            float av[8] = {a0.x, a0.y, a0.z, a0.w, a1.x, a1.y, a1.z, a1.w};
            float bw[8] = {b0.x, b0.y, b0.z, b0.w, b1.x, b1.y, b1.z, b1.w};
#pragma unroll
            for (int i = 0; i < 8; ++i)
#pragma unroll
                for (int j = 0; j < 8; ++j) acc[i][j] += av[i] * bw[j];
        }
        __syncthreads();
    }

#pragma unroll
    for (int rh = 0; rh < 2; ++rh)
#pragma unroll
        for (int i = 0; i < 4; ++i) {
            int row = row0 + rh * 64 + ty * 4 + i;
            float* dst = vpart + ((size_t)ks * N + row) * DV;
#pragma unroll
            for (int ch = 0; ch < 2; ++ch) {
                float4 o;
                o.x = acc[rh * 4 + i][ch * 4 + 0];
                o.y = acc[rh * 4 + i][ch * 4 + 1];
                o.z = acc[rh * 4 + i][ch * 4 + 2];
                o.w = acc[rh * 4 + i][ch * 4 + 3];
                *reinterpret_cast<float4*>(dst + ch * 64 + tx * 4) = o;
            }
        }
}

// ---------------------------------------------------------------------------
// Front device body: s_src/s_dst for 32 rows starting at fb*32
// ---------------------------------------------------------------------------
__device__ __forceinline__ void front_body(int fb, int tid,
                                           const float* __restrict__ x,
                                           const float* __restrict__ W,
                                           const float* __restrict__ b,
                                           const float* __restrict__ a,
                                           float* __restrict__ s_src,
                                           float* __restrict__ s_dst,
                                           float* sa, float* sus, float* sud, float* sc) {
    sa[tid] = a[tid];
    __syncthreads();
    {
        float p = 0.0f;
        if (tid < 64)        p = b[tid] * sa[tid] + b[tid + 64] * sa[tid + 64];
        else if (tid < 128) { int l = tid - 64; p = b[l] * sa[DK + l] + b[l + 64] * sa[DK + 64 + l]; }
#pragma unroll
        for (int off = 32; off > 0; off >>= 1) p += __shfl_down(p, off);
        if (tid == 0)  sc[0] = p;
        if (tid == 64) sc[1] = p;
    }
#pragma unroll
    for (int half = 0; half < 2; ++half) {
        int d = tid + half * 256;
        float us = 0.0f, ud = 0.0f;
#pragma unroll 4
        for (int k = 0; k < DK; ++k) {
            float w = W[(size_t)k * DIM + d];
            us += w * sa[k];
            ud += w * sa[DK + k];
        }
        int dp = d + (d >> 6) * 4;
        sus[dp] = us;
        sud[dp] = ud;
    }
    __syncthreads();
    int r   = tid >> 3;
    int seg = tid & 7;
    int row = fb * 32 + r;
    const float* xr = x + (size_t)row * DIM;
    int base  = seg * 64;
    int baseP = base + seg * 4;
    float accs = 0.0f, accd = 0.0f;
#pragma unroll
    for (int i = 0; i < 16; ++i) {
        float4 q  = *reinterpret_cast<const float4*>(xr + base + i * 4);
        float4 u4 = *reinterpret_cast<const float4*>(&sus[baseP + i * 4]);
        float4 w4 = *reinterpret_cast<const float4*>(&sud[baseP + i * 4]);
        accs += q.x * u4.x + q.y * u4.y + q.z * u4.z + q.w * u4.w;
        accd += q.x * w4.x + q.y * w4.y + q.z * w4.z + q.w * w4.w;
    }
#pragma unroll
    for (int off = 4; off > 0; off >>= 1) {
        accs += __shfl_down(accs, off);
        accd += __shfl_down(accd, off);
    }
    if (seg == 0) {
        s_src[row] = accs + sc[0];
        s_dst[row] = accd + sc[1];
    }
}

// ---------------------------------------------------------------------------
// K1 fused: blocks [0,256) = v-partial GEMM (ksplit=4); [256,512) = front.
// ---------------------------------------------------------------------------
__global__ __launch_bounds__(256) void k_frontv(const float* __restrict__ x,
                                                const float* __restrict__ W,
                                                const float* __restrict__ b,
                                                const float* __restrict__ a,
                                                const float* __restrict__ Wv,
                                                float* __restrict__ s_src,
                                                float* __restrict__ s_dst,
                                                float* __restrict__ vpart) {
    __shared__ float At[BK][LDT];
    __shared__ float Bt[BK][LDT];
    __shared__ float sa[2 * DK];
    __shared__ float sus[DIM + 32], sud[DIM + 32];
    __shared__ float sc[2];
    int blk = blockIdx.x;
    int tid = threadIdx.x;
    if (blk < 256) {
        gemm_body(blk & 63, blk >> 6, KSUB, tid, x, Wv, vpart, At, Bt);
    } else {
        front_body(blk - 256, tid, x, W, b, a, s_src, s_dst, sa, sus, sud, sc);
    }
}

// Legacy standalone kernels (fallback when workspace is tight)
__global__ __launch_bounds__(256) void k_front(const float* __restrict__ x,
                                               const float* __restrict__ W,
                                               const float* __restrict__ b,
                                               const float* __restrict__ a,
                                               float* __restrict__ s_src,
                                               float* __restrict__ s_dst) {
    __shared__ float sa[2 * DK];
    __shared__ float sus[DIM + 32], sud[DIM + 32];
    __shared__ float sc[2];
    front_body(blockIdx.x, threadIdx.x, x, W, b, a, s_src, s_dst, sa, sus, sud, sc);
}

__global__ __launch_bounds__(256) void k_v(const float* __restrict__ x,
                                           const float* __restrict__ Wv,
                                           float* __restrict__ vpart, int ksplit) {
    __shared__ float At[BK][LDT];
    __shared__ float Bt[BK][LDT];
    gemm_body(blockIdx.x & 63, blockIdx.x >> 6, DIM / ksplit, threadIdx.x, x, Wv, vpart, At, Bt);
}

// ---------------------------------------------------------------------------
// K2: rank + scatter fused (conflict-free: seg-groups read consecutive f4).
// ---------------------------------------------------------------------------
__global__ __launch_bounds__(256) void k_rank_scatter(const float* __restrict__ s_dst,
                                                      float* __restrict__ d_sorted,
                                                      int* __restrict__ perm) {
    __shared__ __align__(16) float sd[N];
    __shared__ int part[256];
    int tid = threadIdx.x;
    for (int t = tid; t < N / 4; t += 256)
        reinterpret_cast<float4*>(sd)[t] = reinterpret_cast<const float4*>(s_dst)[t];
    __syncthreads();
    int j0  = blockIdx.x * 16;
    int jj  = tid >> 4;
    int seg = tid & 15;
    int j   = j0 + jj;
    float dj = sd[j];
    int cnt = 0;
    const float4* sdv = reinterpret_cast<const float4*>(sd);
    for (int c = 0; c < 128; ++c) {
        int f4 = c * 16 + seg;
        float4 q = sdv[f4];
        int i0 = f4 * 4;
        cnt += (q.x < dj || (q.x == dj && (i0 + 0) < j));
        cnt += (q.y < dj || (q.y == dj && (i0 + 1) < j));
        cnt += (q.z < dj || (q.z == dj && (i0 + 2) < j));
        cnt += (q.w < dj || (q.w == dj && (i0 + 3) < j));
    }
    part[tid] = cnt;
    __syncthreads();
    if (tid < 16) {
        int s = 0;
#pragma unroll
        for (int t = 0; t < 16; ++t) s += part[tid * 16 + t];
        int jw = j0 + tid;
        d_sorted[s] = sd[jw];
        perm[s] = jw;
    }
}

// ---------------------------------------------------------------------------
// Shared gather: reduce vpart rows of chunk ch (sorted order) + bias into sv,
// exp factors into se1/se2.
// ---------------------------------------------------------------------------
__device__ __forceinline__ void gather_chunk(int ch, int tid, int ksplit,
                                             const float* __restrict__ vpart,
                                             const float* __restrict__ bv,
                                             const float* __restrict__ d_sorted,
                                             const int* __restrict__ perm,
                                             float (*sv)[DV], float* se1, float* se2) {
    float dmax = d_sorted[N - 1];
    if (tid < CHSZ) {
        float d = d_sorted[ch * CHSZ + tid];
        se1[tid] = expf(d - dmax);
        se2[tid] = expf(SLOPE * d);
    }
    __syncthreads();
    int g  = tid >> 5;
    int c4 = tid & 31;
    float4 bb = reinterpret_cast<const float4*>(bv)[c4];
#pragma unroll
    for (int half = 0; half < 2; ++half) {
        int rl = half * 8 + g;
        int r  = ch * CHSZ + rl;
        int j  = perm[r];
        float4 s = {0.f, 0.f, 0.f, 0.f};
        for (int ksp = 0; ksp < ksplit; ++ksp) {
            float4 q = *reinterpret_cast<const float4*>(vpart + ((size_t)ksp * N + j) * DV + c4 * 4);
            s.x += q.x; s.y += q.y; s.z += q.z; s.w += q.w;
        }
        s.x += bb.x; s.y += bb.y; s.z += bb.z; s.w += bb.w;
        *reinterpret_cast<float4*>(&sv[rl][c4 * 4]) = s;
    }
    __syncthreads();
}

// ---------------------------------------------------------------------------
// K3: chunk totals only (no Y spill). 512 blocks.
// ---------------------------------------------------------------------------
__global__ __launch_bounds__(256) void k_vredT(const float* __restrict__ vpart,
                                               const float* __restrict__ bv,
                                               const float* __restrict__ d_sorted,
                                               const int* __restrict__ perm,
                                               double* __restrict__ chunk_tot,
                                               int ksplit) {
    __shared__ float sv[CHSZ][DV];
    __shared__ float se1[CHSZ], se2[CHSZ];
    int ch  = blockIdx.x;
    int tid = threadIdx.x;
    gather_chunk(ch, tid, ksplit, vpart, bv, d_sorted, perm, sv, se1, se2);
    int col = tid & 127;
    bool is2 = tid >= 128;
    double acc = 0.0;
#pragma unroll
    for (int k = 0; k < CHSZ; ++k) {
        float e = is2 ? se2[k] : se1[k];
        acc += (double)(e * sv[k][col]);
    }
    chunk_tot[(size_t)ch * NCOL + tid] = acc;
    if (tid == 0) {
        double z = 0.0;
#pragma unroll
        for (int k = 0; k < CHSZ; ++k) z += (double)se1[k];
        chunk_tot[(size_t)ch * NCOL + 256] = z;
    }
    if (tid == 1) {
        double z = 0.0;
#pragma unroll
        for (int k = 0; k < CHSZ; ++k) z += (double)se2[k];
        chunk_tot[(size_t)ch * NCOL + 257] = z;
    }
}

// ---------------------------------------------------------------------------
// K4: cross-chunk exclusive scan (258 blocks x 256 thr, pair Hillis-Steele).
// ---------------------------------------------------------------------------
__global__ __launch_bounds__(256) void k_coff(const double* __restrict__ chunk_tot,
                                              double* __restrict__ chunk_off,
                                              double* __restrict__ totals) {
    __shared__ double sp[256];
    int col = blockIdx.x;
    int tid = threadIdx.x;
    double v0 = chunk_tot[(size_t)(2 * tid) * NCOL + col];
    double v1 = chunk_tot[(size_t)(2 * tid + 1) * NCOL + col];
    double p = v0 + v1;
    sp[tid] = p;
    __syncthreads();
    for (int off = 1; off < 256; off <<= 1) {
        double t = (tid >= off) ? sp[tid - off] : 0.0;
        __syncthreads();
        sp[tid] += t;
        __syncthreads();
    }
    double excl = sp[tid] - p;
    chunk_off[(size_t)(2 * tid) * NCOL + col]     = excl;
    chunk_off[(size_t)(2 * tid + 1) * NCOL + col] = excl + v0;
    if (tid == 255) totals[col] = sp[255];
}

// ---------------------------------------------------------------------------
// K5: within-chunk exclusive scans; re-gathers vpart (no Y intermediate).
// ---------------------------------------------------------------------------
__global__ __launch_bounds__(256) void k_scanW2(const float* __restrict__ vpart,
                                                const float* __restrict__ bv,
                                                const float* __restrict__ d_sorted,
                                                const int* __restrict__ perm,
                                                const double* __restrict__ chunk_off,
                                                float* __restrict__ P1,
                                                float* __restrict__ P2,
                                                double* __restrict__ pz1,
                                                double* __restrict__ pz2,
                                                int ksplit) {
    __shared__ float sv[CHSZ][DV];
    __shared__ float se1[CHSZ], se2[CHSZ];
    int ch  = blockIdx.x;
    int tid = threadIdx.x;
    gather_chunk(ch, tid, ksplit, vpart, bv, d_sorted, perm, sv, se1, se2);
    int col = tid & 127;
    bool is2 = tid >= 128;
    const float* se = is2 ? se2 : se1;
    float* P        = is2 ? P2  : P1;
    double acc = chunk_off[(size_t)ch * NCOL + tid];
#pragma unroll
    for (int k = 0; k < CHSZ; ++k) {
        P[(size_t)(ch * CHSZ + k) * DV + col] = (float)acc;
        acc += (double)(se[k] * sv[k][col]);
    }
    if (tid < 2) {
        double z = chunk_off[(size_t)ch * NCOL + 256 + tid];
        const float* sez = (tid == 0) ? se1 : se2;
        double* pz = (tid == 0) ? pz1 : pz2;
#pragma unroll
        for (int k = 0; k < CHSZ; ++k) {
            pz[ch * CHSZ + k] = z;
            z += (double)sez[k];
        }
    }
}

// ---------------------------------------------------------------------------
// K6: finalize. 1024 blocks x 256 thr; 8 rows/block; searches hoisted.
// ---------------------------------------------------------------------------
__global__ __launch_bounds__(256) void k_final(const float* __restrict__ s_src,
                                               const float* __restrict__ d_sorted,
                                               const float* __restrict__ P1,
                                               const float* __restrict__ P2,
                                               const double* __restrict__ pz1,
                                               const double* __restrict__ pz2,
                                               const double* __restrict__ totals,
                                               float* __restrict__ out) {
    __shared__ int ski[8];
    __shared__ float ssi[8];
    int tid = threadIdx.x;
    int rbase = blockIdx.x * 8;
    if (tid < 8) {
        int row = rbase + tid;
        float si = s_src[row];
        float thr = -si;
        int lo = 0, hi = N;
        while (lo < hi) {
            int mid = (lo + hi) >> 1;
            if (d_sorted[mid] <= thr) lo = mid + 1; else hi = mid;
        }
        ski[tid] = lo;
        ssi[tid] = si;
    }
    __syncthreads();
    float dmax = d_sorted[N - 1];
    int dv = tid & 127;
    int half = tid >> 7;
    double T1 = totals[dv];
    double T2 = totals[128 + dv];
    double z1T = totals[256], z2T = totals[257];
#pragma unroll
    for (int it = 0; it < 4; ++it) {
        int r2 = it * 2 + half;
        int row = rbase + r2;
        float si = ssi[r2];
        int ki = ski[r2];
        float t = si + dmax;
        float m = t > 0.0f ? t : SLOPE * t;
        float alpha = expf(t - m);
        float beta  = expf(SLOPE * si - m);
        double suf1, sufz1, pre2, prez2;
        if (ki < N) {
            suf1  = T1 - (double)P1[(size_t)ki * DV + dv];
            sufz1 = z1T - pz1[ki];
            pre2  = (double)P2[(size_t)ki * DV + dv];
            prez2 = pz2[ki];
        } else {
            suf1 = 0.0; sufz1 = 0.0; pre2 = T2; prez2 = z2T;
        }
        double num = (double)alpha * suf1  + (double)beta * pre2;
        double den = (double)alpha * sufz1 + (double)beta * prez2;
        out[(size_t)row * DV + dv] = (float)(num / den);
    }
}

// ---------------------------------------------------------------------------
extern "C" void kernel_launch(void* const* d_in, const int* in_sizes, int n_in,
                              void* d_out, int out_size, void* d_ws, size_t ws_size,
                              hipStream_t stream) {
    const float* x  = (const float*)d_in[0];
    const float* W  = (const float*)d_in[1];
    const float* b  = (const float*)d_in[2];
    const float* Wv = (const float*)d_in[3];
    const float* bv = (const float*)d_in[4];
    const float* a  = (const float*)d_in[5];
    float* out = (float*)d_out;

    char* base = (char*)d_ws;
    size_t off = 0;
    auto carve = [&](size_t bytes) -> void* {
        void* p = base + off;
        off = (off + bytes + 255) & ~(size_t)255;
        return p;
    };
    float*  s_src     = (float*)carve(N * sizeof(float));
    float*  s_dst     = (float*)carve(N * sizeof(float));
    float*  d_sorted  = (float*)carve(N * sizeof(float));
    int*    perm      = (int*)carve(N * sizeof(int));
    double* pz1       = (double*)carve(N * sizeof(double));
    double* pz2       = (double*)carve(N * sizeof(double));
    double* chunk_tot = (double*)carve((size_t)NCH * NCOL * sizeof(double));
    double* chunk_off = (double*)carve((size_t)NCH * NCOL * sizeof(double));
    double* totals    = (double*)carve(NCOL * sizeof(double));

    // vpart lifetime now overlaps P1/P2 (k_scanW2 reads vpart while writing P)
    // -> NO aliasing. ksplit=4 path needs 4+2 = 6 planes (24 MB) beyond the
    // small buffers; guarded fallback to ksplit=2 (4 planes) if ws is tight.
    const size_t planeB = (size_t)N * DV * sizeof(float);   // 4 MB
    size_t avail = ws_size > off ? ws_size - off : 0;
    bool fused = avail >= 6 * planeB + 4096;
    int ksplit = fused ? KSPLIT : 2;
    float* vpart = (float*)carve((size_t)ksplit * planeB);
    float* P1    = (float*)carve(planeB);
    float* P2    = (float*)carve(planeB);

    if (fused) {
        k_frontv<<<512, 256, 0, stream>>>(x, W, b, a, Wv, s_src, s_dst, vpart);
    } else {
        k_front<<<N / 32, 256, 0, stream>>>(x, W, b, a, s_src, s_dst);
        k_v<<<64 * ksplit, 256, 0, stream>>>(x, Wv, vpart, ksplit);
    }
    k_rank_scatter<<<N / 16, 256, 0, stream>>>(s_dst, d_sorted, perm);
    k_vredT<<<NCH, 256, 0, stream>>>(vpart, bv, d_sorted, perm, chunk_tot, ksplit);
    k_coff<<<NCOL, 256, 0, stream>>>(chunk_tot, chunk_off, totals);
    k_scanW2<<<NCH, 256, 0, stream>>>(vpart, bv, d_sorted, perm, chunk_off, P1, P2, pz1, pz2, ksplit);
    k_final<<<N / 8, 256, 0, stream>>>(s_src, d_sorted, P1, P2, pz1, pz2, totals, out);
}